// Round 8
// baseline (1139.916 us; speedup 1.0000x reference)
//
#include <hip/hip_runtime.h>
#include <math.h>
#include <stdint.h>

// ---------------------------------------------------------------------------
// Muskingum-Cunge tree routing, spatially-pipelined persistent kernel, v8.
//
// v7 post-mortem: multiplicative tracking ACROSS substeps compounds clamp
// errors within the step (oscillatory map, Qref ratios 2-4x routine at
// level 0) -> 4% systematic outlet bias. v8 abandons tracking entirely:
//   - substeps 0,1: bit-exact hw log2/exp2/rcp at the true Qref (v5 path).
//   - substeps 2,3: PREDICT Qref via fma-only predictor (q~ = max(ti+phi0*z,0),
//     phi0 = 1-2*DT*rD0 exact), evaluate the full hw chains at the predicted
//     points CONCURRENTLY with substep 1's chain, then snap to the true Qref
//     with a deg-4 (1+d)^e correction (d = (Qref-Qref~)/Qref~, clamped +-0.5)
//     and one Newton step on rD. Errors are per-substep, non-accumulating,
//     bounded (deg-4 residual at d=0.5: 0.28% in K2 -> ~7e-4*z in q).
// Transcendental latency of substeps 2,3 moves OFF the serial chain.
//
// Protocol unchanged from v5: per-level persistent blocks, batched (8-step)
// ring handoff, tagged 8-byte relaxed agent-scope atomics (sc0 sc1,
// MALL-coherent, no bulk cache maintenance), next-batch register prefetch,
// per-wave progress counters, no barriers/fences in the steady path.
// ---------------------------------------------------------------------------

#define N_LEVELS   14
#define T_STEPS    2048
#define NR_TOTAL   16383
#define DT_SUB_F   21600.0f
#define EPS_F      1e-6f
#define NBLOCKS    71
#define CTR_STRIDE 8             // ints per wave counter (32 B apart)
#define RING_BYTE_OFF 16384
#define BATCH      8
#define NBATCH     (T_STEPS / BATCH)

__device__ __constant__ int kSize[N_LEVELS] = {8192,4096,2048,1024,512,256,128,64,32,16,8,4,2,1};
__device__ __constant__ int kEpb [N_LEVELS] = {256,256,256,256,256,256,128,64,32,16,8,4,2,1};
__device__ __constant__ int kBlkStart[N_LEVELS+1] = {0,32,48,56,60,62,63,64,65,66,67,68,69,70,71};
__device__ __constant__ int kOffL[N_LEVELS] = {0,8192,12288,14336,15360,15872,16128,16256,16320,16352,16368,16376,16380,16382};
// pair-sum entries before level l
__device__ __constant__ int kOffH[N_LEVELS-1] = {0,4096,6144,7168,7680,7936,8064,8128,8160,8176,8184,8188,8190};

#if __has_builtin(__builtin_amdgcn_exp2f)
#define FAST_EXP2(x) __builtin_amdgcn_exp2f(x)
#else
#define FAST_EXP2(x) exp2f(x)
#endif
#if __has_builtin(__builtin_amdgcn_logf)
#define FAST_LOG2(x) __builtin_amdgcn_logf(x)
#else
#define FAST_LOG2(x) log2f(x)
#endif
#if __has_builtin(__builtin_amdgcn_rcpf)
#define FAST_RCP(x) __builtin_amdgcn_rcpf(x)
#else
#define FAST_RCP(x) (1.0f/(x))
#endif

#define ATOMIC_LD_RLX(p)   __hip_atomic_load((p), __ATOMIC_RELAXED, __HIP_MEMORY_SCOPE_AGENT)
#define ATOMIC_ST_RLX(p,v) __hip_atomic_store((p), (v), __ATOMIC_RELAXED, __HIP_MEMORY_SCOPE_AGENT)

__global__ __launch_bounds__(256)
void mc_route_pipe8(const float* __restrict__ lat,
                    const float* __restrict__ logn,
                    const float* __restrict__ len,
                    const float* __restrict__ slope,
                    const float* __restrict__ wcoef,
                    const float* __restrict__ wexp,
                    const float* __restrict__ dcoef,
                    const float* __restrict__ dexp,
                    float* __restrict__ out,
                    int* __restrict__ prog,
                    unsigned long long* __restrict__ ring,
                    int slotsB)
{
    const int bid = blockIdx.x;
    const int tid = threadIdx.x;

    int lvl = 0;
#pragma unroll
    for (int l = 1; l < N_LEVELS; ++l)
        if (bid >= kBlkStart[l]) lvl = l;

    const int  bl     = bid - kBlkStart[lvl];
    const int  epb    = kEpb[lvl];
    const int  size   = kSize[lvl];
    const bool validT = (tid < epb);
    const int  e      = bl * epb + (validT ? tid : (epb - 1));
    const int  rr     = kOffL[lvl] + e;

    // -------- per-reach constants (chain-fused form, v5-verified) ----------
    // K2 = 2*dx/c            = exp2( eK*lq + cK2 )
    // tX = Qref/(2*c*w*S*dx) = exp2( et*lq + ct )
    const float dx      = len[rr];
    const float S       = slope[rr];
    const float sqrtS_n = sqrtf(S) * expf(-logn[rr]);        // sqrt(S)/n
    const float de23    = 0.66666667f * dexp[rr];
    const float l2dc    = log2f(dcoef[rr]);
    const float l2base  = log2f(0.6f / sqrtS_n) - 0.66666667f * l2dc;
    const float eK      = -de23;
    const float cK2     = log2f(2.0f * dx) + l2base;
    const float et      = 1.0f - de23 - wexp[rr];
    const float ct      = log2f(0.5f / (S * dx)) + l2base - log2f(wcoef[rr]);
    // deg-4 Taylor coefficients for (1+d)^e
    const float aK2 = 0.5f  * eK  * (eK - 1.0f);
    const float aK3 = aK2   * (eK - 2.0f) * 0.33333333f;
    const float aK4 = aK3   * (eK - 3.0f) * 0.25f;
    const float aT2 = 0.5f  * et  * (et - 1.0f);
    const float aT3 = aT2   * (et - 2.0f) * 0.33333333f;
    const float aT4 = aT3   * (et - 3.0f) * 0.25f;

    // -------- pipeline wiring ----------------------------------------------
    const bool hasProd = (lvl > 0);
    const bool hasCons = (lvl < N_LEVELS - 1);
    const int  SB8     = slotsB * BATCH;
    const int  sBm1    = slotsB - 1;
    const unsigned long long* ringUp = hasProd ? ring + (size_t)kOffH[lvl-1] * SB8 : ring;
    unsigned long long*       ringMy = hasCons ? ring + (size_t)kOffH[lvl]   * SB8 : ring;
    const int halfSize = size >> 1;
    const int upSlotSz = size * BATCH;
    const int mySlotSz = halfSize * BATCH;

    int c0i = 0, c1i = 0;
    if (hasCons) {
        const int ceLo = (bl * epb) >> 1;
        const int ceHi = ((bl + 1) * epb - 1) >> 1;
        const int epbN = kEpb[lvl+1];
        const int cb   = kBlkStart[lvl+1] + ceLo / epbN;
        const int le0  = ceLo - (ceLo / epbN) * epbN;
        const int le1  = ceHi - (ceHi / epbN) * epbN;
        c0i = (cb * 4 + (le0 >> 6)) * CTR_STRIDE;
        c1i = (cb * 4 + (le1 >> 6)) * CTR_STRIDE;
    }
    const int  myCtr    = (bid * 4 + (tid >> 6)) * CTR_STRIDE;
    const bool waveLead = ((tid & 63) == 0);

    float Q = 0.0f, Ip = 0.0f;
    int cachedCons = -0x40000000;

    // -------- prologue: load batch 0 ---------------------------------------
    float latCur[BATCH], latNxt[BATCH];
    unsigned long long pendCur[BATCH], pendNxt[BATCH];
#pragma unroll
    for (int j = 0; j < BATCH; ++j)
        latCur[j] = lat[(size_t)j * NR_TOTAL + rr];
    if (hasProd && validT) {
#pragma unroll
        for (int j = 0; j < BATCH; ++j)
            pendCur[j] = ATOMIC_LD_RLX(ringUp + (size_t)j * size + e);
    }

    for (int bi = 0; bi < NBATCH; ++bi) {
        const int tb = bi * BATCH;

        // ---- prefetch NEXT batch (hidden under this batch's compute) ------
        if (bi + 1 < NBATCH) {
#pragma unroll
            for (int j = 0; j < BATCH; ++j)
                latNxt[j] = lat[(size_t)(tb + BATCH + j) * NR_TOTAL + rr];
            if (hasProd && validT) {
                const unsigned long long* upN =
                    ringUp + (size_t)((bi + 1) & sBm1) * upSlotSz + e;
#pragma unroll
                for (int j = 0; j < BATCH; ++j)
                    pendNxt[j] = ATOMIC_LD_RLX(upN + j * size);
            }
        }

        // ---- prefetch consumer progress (non-blocking) --------------------
        int pfCons = -0x40000000;
        const int need = (bi - slotsB + 1) * BATCH;
        if (hasCons && bi >= slotsB && cachedCons < need) {
            int v0 = ATOMIC_LD_RLX(&prog[c0i]);
            int v1 = (c1i == c0i) ? v0 : ATOMIC_LD_RLX(&prog[c1i]);
            pfCons = (v0 < v1) ? v0 : v1;
        }

        // ---- verify current-batch tags (steady state: all match) ----------
        if (hasProd && validT) {
            const unsigned long long* upC =
                ringUp + (size_t)(bi & sBm1) * upSlotSz + e;
#pragma unroll
            for (int j = 0; j < BATCH; ++j) {
                const unsigned tagWant = (unsigned)(tb + j + 1);
                unsigned long long v = pendCur[j];
                int spin = 0;
                while ((unsigned)(v >> 32) != tagWant) {
                    if (((++spin) & 63) == 0) __builtin_amdgcn_s_sleep(1);
                    v = ATOMIC_LD_RLX(upC + (size_t)j * size);
                }
                pendCur[j] = v;
            }
        }

        // ---- compute the 8 steps ------------------------------------------
        float qs[BATCH];
#pragma unroll
        for (int j = 0; j < BATCH; ++j) {
            float inflow = latCur[j];
            if (hasProd && validT)
                inflow += __uint_as_float((unsigned)pendCur[j]);

            const float ti  = inflow;
            const float t23 = ti * (2.0f/3.0f);
            const float dti = (2.0f * DT_SUB_F) * ti;

            // ---- substep 0: exact ------------------------------------
            float q1, rD0;
            {
                const float io = Ip;
                const float q0 = Q;
                float Qref = fmaxf((ti + io + q0) * (1.0f/3.0f), EPS_F);
                float lq   = FAST_LOG2(Qref);
                float K2   = FAST_EXP2(fmaf(eK, lq, cK2));
                float tX   = FAST_EXP2(fmaf(et, lq, ct));
                float KX2  = K2 * fmaxf(0.5f - tX, 0.0f);
                float A    = K2 * fminf(0.5f + tX, 1.0f);
                rD0        = FAST_RCP(A + DT_SUB_F);
                float num  = fmaf(A, q0, fmaf(KX2, io - ti,
                                   DT_SUB_F * ((ti + io) - q0)));
                q1 = fmaxf(num * rD0, 0.0f);
            }

            // ---- predictor for substeps 2,3 (fma-only, from q1) ------
            // phi0 = (A0-DT)/(A0+DT) = 1 - 2*DT*rD0  (exact)
            float phi  = fmaf(-2.0f * DT_SUB_F, rD0, 1.0f);
            float qp2  = fmaxf(fmaf(phi, q1 - ti, ti), 0.0f);
            float Qp2  = fmaxf(fmaf(qp2, 1.0f/3.0f, t23), EPS_F);
            float qp3  = fmaxf(fmaf(phi, qp2 - ti, ti), 0.0f);
            float Qp3  = fmaxf(fmaf(qp3, 1.0f/3.0f, t23), EPS_F);
            // hw-exact chains at the predicted points (run concurrently
            // with substep 1's chain below — independent dataflow)
            float lqp2   = FAST_LOG2(Qp2);
            float K2p2   = FAST_EXP2(fmaf(eK, lqp2, cK2));
            float tXp2   = FAST_EXP2(fmaf(et, lqp2, ct));
            float invQp2 = FAST_RCP(Qp2);
            float Ap2    = K2p2 * fminf(0.5f + tXp2, 1.0f);
            float rDp2   = FAST_RCP(Ap2 + DT_SUB_F);
            float lqp3   = FAST_LOG2(Qp3);
            float K2p3   = FAST_EXP2(fmaf(eK, lqp3, cK2));
            float tXp3   = FAST_EXP2(fmaf(et, lqp3, ct));
            float invQp3 = FAST_RCP(Qp3);
            float Ap3    = K2p3 * fminf(0.5f + tXp3, 1.0f);
            float rDp3   = FAST_RCP(Ap3 + DT_SUB_F);

            // ---- substep 1: exact ------------------------------------
            float q2;
            {
                float Qref = fmaxf(fmaf(q1, 1.0f/3.0f, t23), EPS_F);
                float lq   = FAST_LOG2(Qref);
                float K2   = FAST_EXP2(fmaf(eK, lq, cK2));
                float tX   = FAST_EXP2(fmaf(et, lq, ct));
                float A    = K2 * fminf(0.5f + tX, 1.0f);
                float rD   = FAST_RCP(A + DT_SUB_F);
                q2 = fmaxf(fmaf(A - DT_SUB_F, q1, dti) * rD, 0.0f);
            }

            // ---- substep 2: predicted + deg-4 snap + rD Newton -------
            float q3;
            {
                float Qref = fmaxf(fmaf(q2, 1.0f/3.0f, t23), EPS_F);
                float d    = (Qref - Qp2) * invQp2;
                d          = fminf(fmaxf(d, -0.5f), 0.5f);
                float pK   = fmaf(d, fmaf(d, fmaf(d, fmaf(d, aK4, aK3), aK2), eK), 1.0f);
                float pT   = fmaf(d, fmaf(d, fmaf(d, fmaf(d, aT4, aT3), aT2), et), 1.0f);
                float K2c  = K2p2 * pK;
                float tXc  = tXp2 * pT;
                float A    = K2c * fminf(0.5f + tXc, 1.0f);
                float rD   = rDp2 * fmaf(-(A + DT_SUB_F), rDp2, 2.0f);
                q3 = fmaxf(fmaf(A - DT_SUB_F, q2, dti) * rD, 0.0f);
            }

            // ---- substep 3: predicted + deg-4 snap + rD Newton -------
            float q4;
            {
                float Qref = fmaxf(fmaf(q3, 1.0f/3.0f, t23), EPS_F);
                float d    = (Qref - Qp3) * invQp3;
                d          = fminf(fmaxf(d, -0.5f), 0.5f);
                float pK   = fmaf(d, fmaf(d, fmaf(d, fmaf(d, aK4, aK3), aK2), eK), 1.0f);
                float pT   = fmaf(d, fmaf(d, fmaf(d, fmaf(d, aT4, aT3), aT2), et), 1.0f);
                float K2c  = K2p3 * pK;
                float tXc  = tXp3 * pT;
                float A    = K2c * fminf(0.5f + tXc, 1.0f);
                float rD   = rDp3 * fmaf(-(A + DT_SUB_F), rDp3, 2.0f);
                q4 = fmaxf(fmaf(A - DT_SUB_F, q3, dti) * rD, 0.0f);
            }

            Q = q4; Ip = inflow;

            if (hasCons) qs[j] = q4 + __shfl_xor(q4, 1);
            else if (tid == 0) out[tb + j] = q4;
        }

        // ---- back-pressure, then store the batch --------------------------
        if (hasCons) {
            if (bi >= slotsB && cachedCons < need) {
                if (pfCons >= need) {
                    cachedCons = pfCons;
                } else {
                    int spin = 0;
                    for (;;) {
                        int v0 = ATOMIC_LD_RLX(&prog[c0i]);
                        int v1 = (c1i == c0i) ? v0 : ATOMIC_LD_RLX(&prog[c1i]);
                        int m  = (v0 < v1) ? v0 : v1;
                        if (m >= need) { cachedCons = m; break; }
                        if (((++spin) & 63) == 0) __builtin_amdgcn_s_sleep(1);
                    }
                }
            }
            if (validT && ((tid & 1) == 0)) {
                unsigned long long* st = ringMy + (size_t)(bi & sBm1) * mySlotSz + (e >> 1);
#pragma unroll
                for (int j = 0; j < BATCH; ++j) {
                    unsigned long long v =
                        ((unsigned long long)(unsigned)(tb + j + 1) << 32) |
                        (unsigned long long)__float_as_uint(qs[j]);
                    ATOMIC_ST_RLX(st + (size_t)j * halfSize, v);
                }
            }
        }

        // ---- publish per-wave consumed progress ---------------------------
        if (waveLead) {
            int pubv = tb + BATCH;
            __asm__ volatile("" : "+v"(pubv) : "v"(Q));  // orders after ring reads
            ATOMIC_ST_RLX(&prog[myCtr], pubv);
        }

        // ---- swap prefetch buffers ----------------------------------------
#pragma unroll
        for (int j = 0; j < BATCH; ++j) {
            latCur[j]  = latNxt[j];
            pendCur[j] = pendNxt[j];
        }
    }
}

extern "C" void kernel_launch(void* const* d_in, const int* in_sizes, int n_in,
                              void* d_out, int out_size, void* d_ws, size_t ws_size,
                              hipStream_t stream) {
    const float* lat   = (const float*)d_in[0];
    const float* logn  = (const float*)d_in[1];
    const float* len   = (const float*)d_in[2];
    const float* slope = (const float*)d_in[3];
    const float* wc    = (const float*)d_in[4];
    const float* we    = (const float*)d_in[5];
    const float* dc    = (const float*)d_in[6];
    const float* de    = (const float*)d_in[7];
    float* out = (float*)d_out;

    int* prog = (int*)d_ws;
    unsigned long long* ring = (unsigned long long*)((char*)d_ws + RING_BYTE_OFF);

    int slotsB = 8;
    while (slotsB > 1) {
        size_t needB = (size_t)RING_BYTE_OFF + (size_t)8191 * 8 * 8 * slotsB;
        if (needB <= ws_size) break;
        slotsB >>= 1;
    }

    mc_route_pipe8<<<NBLOCKS, 256, 0, stream>>>(lat, logn, len, slope, wc, we, dc, de,
                                                out, prog, ring, slotsB);
}